// Round 1
// baseline (375.843 us; speedup 1.0000x reference)
//
#include <hip/hip_runtime.h>

typedef __bf16 bf16x8 __attribute__((ext_vector_type(8)));
typedef float f32x4 __attribute__((ext_vector_type(4)));
typedef unsigned int u32x4 __attribute__((ext_vector_type(4)));
typedef unsigned int u32x2 __attribute__((ext_vector_type(2)));

#define HW 14400
#define CIN 192

__device__ __forceinline__ unsigned short f2bf(float f) {
  unsigned int u = __builtin_bit_cast(unsigned int, f);
  u = (u + 0x7FFFu + ((u >> 16) & 1u)) >> 16;
  return (unsigned short)u;
}
__device__ __forceinline__ float bf2f(unsigned short h) {
  unsigned int u = ((unsigned int)h) << 16;
  return __builtin_bit_cast(float, u);
}

// ---------------- prep: fold BN into conv weights, convert to bf16 ----------
__global__ void prep_kernel(const float* __restrict__ w_in, const float* __restrict__ b_in,
                            const float* __restrict__ g, const float* __restrict__ be,
                            const float* __restrict__ mu, const float* __restrict__ va,
                            const float* __restrict__ w_out,
                            unsigned short* __restrict__ wx, unsigned short* __restrict__ wy,
                            unsigned short* __restrict__ wo,
                            float* __restrict__ bx, float* __restrict__ by) {
  int idx = blockIdx.x * 256 + threadIdx.x;
  if (idx < 384 * 192) {
    int o = idx / 192;
    float s = g[o] * rsqrtf(va[o] + 1e-5f);
    wx[idx] = f2bf(w_in[idx] * s);
  } else if (idx < 384 * 192 + 192 * 192) {
    int j = idx - 384 * 192;
    int jo = j / 192, c = j % 192;
    int o = (jo >> 6) * 128 + (jo & 63);   // q-channel rows only
    float s = g[o] * rsqrtf(va[o] + 1e-5f);
    wy[j] = f2bf(w_in[o * 192 + c] * s);
  } else if (idx < 384 * 192 + 2 * 192 * 192) {
    int j = idx - (384 * 192 + 192 * 192);
    wo[j] = f2bf(w_out[j]);
  }
  if (idx < 384) {
    float s = g[idx] * rsqrtf(va[idx] + 1e-5f);
    bx[idx] = (b_in[idx] - mu[idx]) * s + be[idx];
  } else if (idx < 384 + 192) {
    int jo = idx - 384;
    int o = (jo >> 6) * 128 + (jo & 63);
    float s = g[o] * rsqrtf(va[o] + 1e-5f);
    by[jo] = (b_in[o] - mu[o]) * s + be[o];
  }
}

// ---------------- conv_in: [b,c,h,w] fp32 -> [px][NOUT] bf16 via MFMA -------
template <int NOUT>
__launch_bounds__(256, 2)
__global__ void conv_in_kernel(const float* __restrict__ X,
                               const unsigned short* __restrict__ Wb,
                               const float* __restrict__ bias,
                               unsigned short* __restrict__ Out) {
  constexpr int NT = NOUT / 64;  // N-tiles per wave
  __shared__ unsigned short a_lds[64 * 40];        // [px][c] padded
  __shared__ unsigned short b_lds[NOUT * 40];      // [o][c] padded
  const int t = threadIdx.x;
  const int wave = t >> 6, lane = t & 63;
  const int l15 = lane & 15, l4 = lane >> 4;
  const int b = blockIdx.x / 225;
  const int px0 = (blockIdx.x % 225) * 64;
  const float* Xb = X + (size_t)b * CIN * HW + px0;
  const int wo0 = wave * (NOUT / 4);

  f32x4 acc[4][NT];
#pragma unroll
  for (int n = 0; n < NT; ++n) {
    float bv = bias[wo0 + n * 16 + l15];
    f32x4 iv = {bv, bv, bv, bv};
#pragma unroll
    for (int m = 0; m < 4; ++m) acc[m][n] = iv;
  }

  for (int kc = 0; kc < 6; ++kc) {
    const int c0 = kc * 32;
#pragma unroll
    for (int p = 0; p < 2; ++p) {  // stage A (transpose to [px][c])
      int idx = p * 256 + t;
      int c = idx >> 4, px4 = (idx & 15) * 4;
      f32x4 v = *reinterpret_cast<const f32x4*>(Xb + (size_t)(c0 + c) * HW + px4);
      a_lds[(px4 + 0) * 40 + c] = f2bf(v[0]);
      a_lds[(px4 + 1) * 40 + c] = f2bf(v[1]);
      a_lds[(px4 + 2) * 40 + c] = f2bf(v[2]);
      a_lds[(px4 + 3) * 40 + c] = f2bf(v[3]);
    }
#pragma unroll
    for (int p = 0; p < NOUT / 64; ++p) {  // stage B (weights)
      int o = p * 64 + (t >> 2), c8 = (t & 3) * 8;
      *reinterpret_cast<u32x4*>(&b_lds[o * 40 + c8]) =
          *reinterpret_cast<const u32x4*>(Wb + (size_t)o * CIN + c0 + c8);
    }
    __syncthreads();
    bf16x8 af[4];
#pragma unroll
    for (int m = 0; m < 4; ++m)
      af[m] = *reinterpret_cast<const bf16x8*>(&a_lds[(m * 16 + l15) * 40 + l4 * 8]);
#pragma unroll
    for (int n = 0; n < NT; ++n) {
      bf16x8 bfr = *reinterpret_cast<const bf16x8*>(&b_lds[(wo0 + n * 16 + l15) * 40 + l4 * 8]);
#pragma unroll
      for (int m = 0; m < 4; ++m)
        acc[m][n] = __builtin_amdgcn_mfma_f32_16x16x32_bf16(af[m], bfr, acc[m][n], 0, 0, 0);
    }
    __syncthreads();
  }

  unsigned short* Ob = Out + ((size_t)b * HW + px0) * NOUT;
#pragma unroll
  for (int m = 0; m < 4; ++m) {
#pragma unroll
    for (int r = 0; r < 4; ++r) {
      int px = m * 16 + l4 * 4 + r;
      unsigned short* dst = Ob + (size_t)px * NOUT + wo0 + l15;
#pragma unroll
      for (int n = 0; n < NT; ++n) dst[n * 16] = f2bf(acc[m][n][r]);
    }
  }
}

// ---------------- attention: gather -> QK^T (MFMA) -> softmax -> PV ---------
template <int WS, int SI, int NTHR>
__launch_bounds__(NTHR, 1)
__global__ void attn_kernel(const unsigned short* __restrict__ XP,
                            const unsigned short* __restrict__ YQ,
                            unsigned short* __restrict__ Z,
                            float* __restrict__ ATN) {
  constexpr int S = WS / 2, L = WS * WS, NH = 120 / WS, TT = L / 16, SL = L + 1;
  constexpr int NWAVE = NTHR / 64;
  __shared__ unsigned short q_lds[L * 72];  // bf16, padded (144B rows, 16B aligned)
  __shared__ unsigned short k_lds[L * 72];
  __shared__ float v_lds[L * 64];           // f32, broadcast reads -> no pad needed
  __shared__ float s_lds[L * SL];
  const int t = threadIdx.x;
  const int win = blockIdx.x;
  const int b = win / (NH * NH);
  const int r_ = win % (NH * NH);
  const int ih = r_ / NH, iw = r_ % NH;

  auto pixof = [&](int e) {
    int p = e / WS, qc = e % WS;
    int h = ih * WS + p + S; if (h >= 120) h -= 120;
    int w = iw * WS + qc + S; if (w >= 120) w -= 120;
    return b * HW + h * 120 + w;
  };

  for (int idx = t; idx < L * 8; idx += NTHR) {   // stage Q + V (from x path)
    int e = idx >> 3, c8 = (idx & 7) * 8;
    size_t base = (size_t)pixof(e) * 384 + SI * 128 + c8;
    u32x4 q = *reinterpret_cast<const u32x4*>(XP + base);
    u32x4 v = *reinterpret_cast<const u32x4*>(XP + base + 64);
    *reinterpret_cast<u32x4*>(&q_lds[e * 72 + c8]) = q;
    const unsigned short* vh = reinterpret_cast<const unsigned short*>(&v);
#pragma unroll
    for (int j = 0; j < 8; ++j) v_lds[e * 64 + c8 + j] = bf2f(vh[j]);
  }
  for (int idx = t; idx < L * 8; idx += NTHR) {   // stage K (from y path)
    int e = idx >> 3, c8 = (idx & 7) * 8;
    *reinterpret_cast<u32x4*>(&k_lds[e * 72 + c8]) =
        *reinterpret_cast<const u32x4*>(YQ + (size_t)pixof(e) * 192 + SI * 64 + c8);
  }
  __syncthreads();

  const int wave = t >> 6, lane = t & 63, l15 = lane & 15, l4 = lane >> 4;
  for (int tile = wave; tile < TT * TT; tile += NWAVE) {  // S = Q K^T
    int ti = tile / TT, tj = tile % TT;
    f32x4 acc = {0.f, 0.f, 0.f, 0.f};
#pragma unroll
    for (int kc = 0; kc < 2; ++kc) {
      bf16x8 a = *reinterpret_cast<const bf16x8*>(&q_lds[(ti * 16 + l15) * 72 + kc * 32 + l4 * 8]);
      bf16x8 bb = *reinterpret_cast<const bf16x8*>(&k_lds[(tj * 16 + l15) * 72 + kc * 32 + l4 * 8]);
      acc = __builtin_amdgcn_mfma_f32_16x16x32_bf16(a, bb, acc, 0, 0, 0);
    }
#pragma unroll
    for (int r = 0; r < 4; ++r)
      s_lds[(ti * 16 + l4 * 4 + r) * SL + tj * 16 + l15] = acc[r];
  }
  __syncthreads();

  for (int i = t; i < L; i += NTHR) {  // row softmax (fp32)
    float m = -1e30f;
    for (int j = 0; j < L; ++j) m = fmaxf(m, s_lds[i * SL + j]);
    float sum = 0.f;
    for (int j = 0; j < L; ++j) {
      float e = __expf(s_lds[i * SL + j] - m);
      s_lds[i * SL + j] = e;
      sum += e;
    }
    float inv = 1.f / sum;
    for (int j = 0; j < L; ++j) s_lds[i * SL + j] *= inv;
  }
  __syncthreads();

  float* aout = ATN + (size_t)win * L * L;   // coalesced atn write
  for (int idx = t; idx < L * L; idx += NTHR)
    aout[idx] = s_lds[(idx / L) * SL + (idx % L)];

  constexpr int RPP = NTHR / 16;             // PV: vector fp32
  const int c4 = (t & 15) * 4, ig = t >> 4;
#pragma unroll 1
  for (int pass = 0; pass < L / RPP; ++pass) {
    int i = pass * RPP + ig;
    f32x4 acc = {0.f, 0.f, 0.f, 0.f};
    for (int j = 0; j < L; ++j) {
      float p = s_lds[i * SL + j];
      f32x4 v = *reinterpret_cast<const f32x4*>(&v_lds[j * 64 + c4]);
      acc = acc + v * p;
    }
    unsigned short* dst = Z + (size_t)pixof(i) * 192 + SI * 64 + c4;
    unsigned int lo = (unsigned int)f2bf(acc[0]) | ((unsigned int)f2bf(acc[1]) << 16);
    unsigned int hi = (unsigned int)f2bf(acc[2]) | ((unsigned int)f2bf(acc[3]) << 16);
    u32x2 pk = {lo, hi};
    *reinterpret_cast<u32x2*>(dst) = pk;
  }
}

// ---------------- conv_out: z [px][192] bf16 -> y1 [b,o,h,w] fp32 -----------
__launch_bounds__(256, 2)
__global__ void conv_out_kernel(const unsigned short* __restrict__ Z,
                                const unsigned short* __restrict__ Wo,
                                const float* __restrict__ bout,
                                float* __restrict__ Y1) {
  __shared__ unsigned short z_lds[64 * 40];
  __shared__ unsigned short w_lds[192 * 40];
  const int t = threadIdx.x, wave = t >> 6, lane = t & 63;
  const int l15 = lane & 15, l4 = lane >> 4;
  const int b = blockIdx.x / 225, px0 = (blockIdx.x % 225) * 64;
  const unsigned short* Zb = Z + ((size_t)b * HW + px0) * 192;
  const int wo0 = wave * 48;
  f32x4 acc[3][4];
#pragma unroll
  for (int m = 0; m < 3; ++m) {
    f32x4 bv;
#pragma unroll
    for (int r = 0; r < 4; ++r) bv[r] = bout[wo0 + m * 16 + l4 * 4 + r];
#pragma unroll
    for (int n = 0; n < 4; ++n) acc[m][n] = bv;
  }
  for (int kc = 0; kc < 6; ++kc) {
    const int c0 = kc * 32;
    {
      int px = t >> 2, c8 = (t & 3) * 8;
      *reinterpret_cast<u32x4*>(&z_lds[px * 40 + c8]) =
          *reinterpret_cast<const u32x4*>(Zb + (size_t)px * 192 + c0 + c8);
    }
#pragma unroll
    for (int p = 0; p < 3; ++p) {
      int o = p * 64 + (t >> 2), c8 = (t & 3) * 8;
      *reinterpret_cast<u32x4*>(&w_lds[o * 40 + c8]) =
          *reinterpret_cast<const u32x4*>(Wo + (size_t)o * 192 + c0 + c8);
    }
    __syncthreads();
    bf16x8 bfr[4];
#pragma unroll
    for (int n = 0; n < 4; ++n)
      bfr[n] = *reinterpret_cast<const bf16x8*>(&z_lds[(n * 16 + l15) * 40 + l4 * 8]);
#pragma unroll
    for (int m = 0; m < 3; ++m) {
      bf16x8 af = *reinterpret_cast<const bf16x8*>(&w_lds[(wo0 + m * 16 + l15) * 40 + l4 * 8]);
#pragma unroll
      for (int n = 0; n < 4; ++n)
        acc[m][n] = __builtin_amdgcn_mfma_f32_16x16x32_bf16(af, bfr[n], acc[m][n], 0, 0, 0);
    }
    __syncthreads();
  }
  float* Yb = Y1 + (size_t)b * 192 * HW + px0;
#pragma unroll
  for (int m = 0; m < 3; ++m) {
#pragma unroll
    for (int r = 0; r < 4; ++r) {
      int o = wo0 + m * 16 + l4 * 4 + r;
      float* dst = Yb + (size_t)o * HW + l15;
#pragma unroll
      for (int n = 0; n < 4; ++n) dst[n * 16] = acc[m][n][r];
    }
  }
}

// ---------------- launch ----------------------------------------------------
extern "C" void kernel_launch(void* const* d_in, const int* in_sizes, int n_in,
                              void* d_out, int out_size, void* d_ws, size_t ws_size,
                              hipStream_t stream) {
  const float* x = (const float*)d_in[0];
  const float* y = (const float*)d_in[1];
  const float* w_in = (const float*)d_in[2];
  const float* b_in = (const float*)d_in[3];
  const float* g = (const float*)d_in[4];
  const float* be = (const float*)d_in[5];
  const float* mu = (const float*)d_in[6];
  const float* va = (const float*)d_in[7];
  const float* w_out = (const float*)d_in[8];
  const float* b_out = (const float*)d_in[9];
  char* ws = (char*)d_ws;
  unsigned short* wx = (unsigned short*)(ws + 0);
  unsigned short* wy = (unsigned short*)(ws + 147456);
  unsigned short* wo = (unsigned short*)(ws + 221184);
  float* bx = (float*)(ws + 294912);
  float* by = (float*)(ws + 296448);
  unsigned short* xp = (unsigned short*)(ws + 297216);
  unsigned short* yq = (unsigned short*)(ws + 297216 + (size_t)115200 * 384 * 2);
  unsigned short* z  = (unsigned short*)(ws + 297216 + (size_t)115200 * 384 * 2 +
                                         (size_t)115200 * 192 * 2);
  float* out = (float*)d_out;

  prep_kernel<<<576, 256, 0, stream>>>(w_in, b_in, g, be, mu, va, w_out, wx, wy, wo, bx, by);
  conv_in_kernel<384><<<1800, 256, 0, stream>>>(x, wx, bx, xp);
  conv_in_kernel<192><<<1800, 256, 0, stream>>>(y, wy, by, yq);
  attn_kernel<4, 0, 64><<<7200, 64, 0, stream>>>(xp, yq, z, out + 22118400);
  attn_kernel<8, 1, 256><<<1800, 256, 0, stream>>>(xp, yq, z, out + 23961600);
  attn_kernel<12, 2, 256><<<800, 256, 0, stream>>>(xp, yq, z, out + 31334400);
  conv_out_kernel<<<1800, 256, 0, stream>>>(z, wo, b_out, out);
}

// Round 2
// 225.540 us; speedup vs baseline: 1.6664x; 1.6664x over previous
//
#include <hip/hip_runtime.h>

typedef __bf16 bf16x8 __attribute__((ext_vector_type(8)));
typedef float f32x4 __attribute__((ext_vector_type(4)));
typedef unsigned int u32x4 __attribute__((ext_vector_type(4)));
typedef unsigned int u32x2 __attribute__((ext_vector_type(2)));

#define HW 14400
#define CIN 192

__device__ __forceinline__ unsigned short f2bf(float f) {
  unsigned int u = __builtin_bit_cast(unsigned int, f);
  u = (u + 0x7FFFu + ((u >> 16) & 1u)) >> 16;
  return (unsigned short)u;
}
__device__ __forceinline__ float bf2f(unsigned short h) {
  unsigned int u = ((unsigned int)h) << 16;
  return __builtin_bit_cast(float, u);
}

// ---------------- prep: fold BN into conv weights, convert to bf16 ----------
__global__ void prep_kernel(const float* __restrict__ w_in, const float* __restrict__ b_in,
                            const float* __restrict__ g, const float* __restrict__ be,
                            const float* __restrict__ mu, const float* __restrict__ va,
                            const float* __restrict__ w_out,
                            unsigned short* __restrict__ wx, unsigned short* __restrict__ wy,
                            unsigned short* __restrict__ wo,
                            float* __restrict__ bx, float* __restrict__ by) {
  int idx = blockIdx.x * 256 + threadIdx.x;
  if (idx < 384 * 192) {
    int o = idx / 192;
    float s = g[o] * rsqrtf(va[o] + 1e-5f);
    wx[idx] = f2bf(w_in[idx] * s);
  } else if (idx < 384 * 192 + 192 * 192) {
    int j = idx - 384 * 192;
    int jo = j / 192, c = j % 192;
    int o = (jo >> 6) * 128 + (jo & 63);   // q-channel rows only
    float s = g[o] * rsqrtf(va[o] + 1e-5f);
    wy[j] = f2bf(w_in[o * 192 + c] * s);
  } else if (idx < 384 * 192 + 2 * 192 * 192) {
    int j = idx - (384 * 192 + 192 * 192);
    wo[j] = f2bf(w_out[j]);
  }
  if (idx < 384) {
    float s = g[idx] * rsqrtf(va[idx] + 1e-5f);
    bx[idx] = (b_in[idx] - mu[idx]) * s + be[idx];
  } else if (idx < 384 + 192) {
    int jo = idx - 384;
    int o = (jo >> 6) * 128 + (jo & 63);
    float s = g[o] * rsqrtf(va[o] + 1e-5f);
    by[jo] = (b_in[o] - mu[o]) * s + be[o];
  }
}

// ---------------- conv_in: [b,c,h,w] fp32 -> [px][NOUT] bf16 via MFMA -------
template <int NOUT>
__launch_bounds__(256, 2)
__global__ void conv_in_kernel(const float* __restrict__ X,
                               const unsigned short* __restrict__ Wb,
                               const float* __restrict__ bias,
                               unsigned short* __restrict__ Out) {
  constexpr int NT = NOUT / 64;  // N-tiles per wave
  __shared__ unsigned short a_lds[64 * 40];        // [px][c] padded
  __shared__ unsigned short b_lds[NOUT * 40];      // [o][c] padded
  const int t = threadIdx.x;
  const int wave = t >> 6, lane = t & 63;
  const int l15 = lane & 15, l4 = lane >> 4;
  const int b = blockIdx.x / 225;
  const int px0 = (blockIdx.x % 225) * 64;
  const float* Xb = X + (size_t)b * CIN * HW + px0;
  const int wo0 = wave * (NOUT / 4);

  f32x4 acc[4][NT];
#pragma unroll
  for (int n = 0; n < NT; ++n) {
    float bv = bias[wo0 + n * 16 + l15];
    f32x4 iv = {bv, bv, bv, bv};
#pragma unroll
    for (int m = 0; m < 4; ++m) acc[m][n] = iv;
  }

  for (int kc = 0; kc < 6; ++kc) {
    const int c0 = kc * 32;
#pragma unroll
    for (int p = 0; p < 2; ++p) {  // stage A (transpose to [px][c])
      int idx = p * 256 + t;
      int c = idx >> 4, px4 = (idx & 15) * 4;
      f32x4 v = *reinterpret_cast<const f32x4*>(Xb + (size_t)(c0 + c) * HW + px4);
      a_lds[(px4 + 0) * 40 + c] = f2bf(v[0]);
      a_lds[(px4 + 1) * 40 + c] = f2bf(v[1]);
      a_lds[(px4 + 2) * 40 + c] = f2bf(v[2]);
      a_lds[(px4 + 3) * 40 + c] = f2bf(v[3]);
    }
#pragma unroll
    for (int p = 0; p < NOUT / 64; ++p) {  // stage B (weights)
      int o = p * 64 + (t >> 2), c8 = (t & 3) * 8;
      *reinterpret_cast<u32x4*>(&b_lds[o * 40 + c8]) =
          *reinterpret_cast<const u32x4*>(Wb + (size_t)o * CIN + c0 + c8);
    }
    __syncthreads();
    bf16x8 af[4];
#pragma unroll
    for (int m = 0; m < 4; ++m)
      af[m] = *reinterpret_cast<const bf16x8*>(&a_lds[(m * 16 + l15) * 40 + l4 * 8]);
#pragma unroll
    for (int n = 0; n < NT; ++n) {
      bf16x8 bfr = *reinterpret_cast<const bf16x8*>(&b_lds[(wo0 + n * 16 + l15) * 40 + l4 * 8]);
#pragma unroll
      for (int m = 0; m < 4; ++m)
        acc[m][n] = __builtin_amdgcn_mfma_f32_16x16x32_bf16(af[m], bfr, acc[m][n], 0, 0, 0);
    }
    __syncthreads();
  }

  unsigned short* Ob = Out + ((size_t)b * HW + px0) * NOUT;
#pragma unroll
  for (int m = 0; m < 4; ++m) {
#pragma unroll
    for (int r = 0; r < 4; ++r) {
      int px = m * 16 + l4 * 4 + r;
      unsigned short* dst = Ob + (size_t)px * NOUT + wo0 + l15;
#pragma unroll
      for (int n = 0; n < NT; ++n) dst[n * 16] = f2bf(acc[m][n][r]);
    }
  }
}

// ---------------- attention v2: reg-resident S, shfl softmax, MFMA PV -------
// S stripes (16 rows) owned per-wave in MFMA accum layout. Softmax via
// __shfl_xor over the 16-lane column group. P -> bf16 LDS (aliases k_lds,
// barrier-protected), PV = MFMA against vt[ch][k] (k zero-padded to KP).
template <int WS, int SI, int NTHR>
__launch_bounds__(NTHR, 2)
__global__ void attn_kernel(const unsigned short* __restrict__ XP,
                            const unsigned short* __restrict__ YQ,
                            unsigned short* __restrict__ Z,
                            float* __restrict__ ATN) {
  constexpr int S = WS / 2, L = WS * WS, NH = 120 / WS, TT = L / 16;
  constexpr int NWAVE = NTHR / 64;
  constexpr int SMAX = (TT + NWAVE - 1) / NWAVE;
  constexpr int KP = ((L + 31) / 32) * 32;   // PV k-dim padded to x32
  constexpr int PL = KP + 8;                 // +8 pad: 2-way-free banks
  constexpr int KSTEPS = KP / 32;
  constexpr int POOLE = (L * 72 > L * PL) ? L * 72 : L * PL;
  __shared__ unsigned short pool[POOLE];     // k_lds then (aliased) p_lds
  __shared__ unsigned short vt_lds[64 * PL]; // V^T: [ch][k]
  unsigned short* k_lds = pool;
  unsigned short* p_lds = pool;

  const int t = threadIdx.x;
  const int win = blockIdx.x;
  const int b = win / (NH * NH);
  const int r_ = win % (NH * NH);
  const int ih = r_ / NH, iw = r_ % NH;
  const int wave = t >> 6, lane = t & 63, l15 = lane & 15, l4 = lane >> 4;

  auto pixof = [&](int e) {
    int p = e / WS, qc = e % WS;
    int h = ih * WS + p + S; if (h >= 120) h -= 120;
    int w = iw * WS + qc + S; if (w >= 120) w -= 120;
    return b * HW + h * 120 + w;
  };

  // ---- stage K rows (bf16) ----
  for (int idx = t; idx < L * 8; idx += NTHR) {
    int e = idx >> 3, c8 = (idx & 7) * 8;
    *reinterpret_cast<u32x4*>(&k_lds[e * 72 + c8]) =
        *reinterpret_cast<const u32x4*>(YQ + (size_t)pixof(e) * 192 + SI * 64 + c8);
  }
  // ---- stage V transposed: vt[ch][k] ----
  for (int idx = t; idx < L * 8; idx += NTHR) {
    int e = idx >> 3, c8 = (idx & 7) * 8;
    u32x4 v = *reinterpret_cast<const u32x4*>(XP + (size_t)pixof(e) * 384 + SI * 128 + 64 + c8);
    const unsigned short* vh = reinterpret_cast<const unsigned short*>(&v);
#pragma unroll
    for (int j = 0; j < 8; ++j) vt_lds[(c8 + j) * PL + e] = vh[j];
  }
  if constexpr (KP > L) {   // zero-fill vt k-pad
    for (int idx = t; idx < 64 * (KP - L); idx += NTHR)
      vt_lds[(idx / (KP - L)) * PL + L + (idx % (KP - L))] = 0;
  }

  // ---- Q fragments straight from global (no reuse) ----
  bf16x8 af[SMAX][2];
#pragma unroll
  for (int si = 0; si < SMAX; ++si) {
    int ti = wave + si * NWAVE;
    if (ti < TT) {
      const unsigned short* qp =
          XP + (size_t)pixof(ti * 16 + l15) * 384 + SI * 128 + l4 * 8;
      af[si][0] = *reinterpret_cast<const bf16x8*>(qp);
      af[si][1] = *reinterpret_cast<const bf16x8*>(qp + 32);
    }
  }
  __syncthreads();

  // ---- QK^T into accumulators ----
  f32x4 sacc[SMAX][TT];
#pragma unroll
  for (int si = 0; si < SMAX; ++si)
#pragma unroll
    for (int tj = 0; tj < TT; ++tj) sacc[si][tj] = f32x4{0.f, 0.f, 0.f, 0.f};
#pragma unroll
  for (int tj = 0; tj < TT; ++tj) {
    bf16x8 b0 = *reinterpret_cast<const bf16x8*>(&k_lds[(tj * 16 + l15) * 72 + l4 * 8]);
    bf16x8 b1 = *reinterpret_cast<const bf16x8*>(&k_lds[(tj * 16 + l15) * 72 + 32 + l4 * 8]);
#pragma unroll
    for (int si = 0; si < SMAX; ++si) {
      int ti = wave + si * NWAVE;
      if (ti < TT) {
        sacc[si][tj] = __builtin_amdgcn_mfma_f32_16x16x32_bf16(af[si][0], b0, sacc[si][tj], 0, 0, 0);
        sacc[si][tj] = __builtin_amdgcn_mfma_f32_16x16x32_bf16(af[si][1], b1, sacc[si][tj], 0, 0, 0);
      }
    }
  }

  // ---- register softmax (rows spread over 16-lane col groups) ----
  float inv_[SMAX][4];
#pragma unroll
  for (int si = 0; si < SMAX; ++si) {
    int ti = wave + si * NWAVE;
    if (ti < TT) {
#pragma unroll
      for (int r = 0; r < 4; ++r) {
        float m = -1e30f;
#pragma unroll
        for (int tj = 0; tj < TT; ++tj) m = fmaxf(m, sacc[si][tj][r]);
#pragma unroll
        for (int mk = 1; mk < 16; mk <<= 1) m = fmaxf(m, __shfl_xor(m, mk, 64));
        float s = 0.f;
#pragma unroll
        for (int tj = 0; tj < TT; ++tj) {
          float e = __expf(sacc[si][tj][r] - m);
          sacc[si][tj][r] = e;
          s += e;
        }
#pragma unroll
        for (int mk = 1; mk < 16; mk <<= 1) s += __shfl_xor(s, mk, 64);
        inv_[si][r] = 1.f / s;
      }
    }
  }

  __syncthreads();  // all waves done reading k_lds -> p_lds may overwrite

  if constexpr (KP > L) {   // zero p k-pad for owned stripes (16 cols)
#pragma unroll
    for (int si = 0; si < SMAX; ++si) {
      int ti = wave + si * NWAVE;
      if (ti < TT)
        *reinterpret_cast<unsigned long long*>(
            &p_lds[(ti * 16 + l15) * PL + L + l4 * 4]) = 0ULL;
    }
  }

  // ---- scale, write atn (fp32) + P (bf16) ----
  float* aout = ATN + (size_t)win * L * L;
#pragma unroll
  for (int si = 0; si < SMAX; ++si) {
    int ti = wave + si * NWAVE;
    if (ti < TT) {
#pragma unroll
      for (int tj = 0; tj < TT; ++tj)
#pragma unroll
        for (int r = 0; r < 4; ++r) {
          float p = sacc[si][tj][r] * inv_[si][r];
          int row = ti * 16 + l4 * 4 + r, col = tj * 16 + l15;
          aout[row * L + col] = p;
          p_lds[row * PL + col] = f2bf(p);
        }
    }
  }
  __syncthreads();

  // ---- PV via MFMA: O[i][ch] = sum_k P[i][k] V[k][ch] ----
#pragma unroll
  for (int si = 0; si < SMAX; ++si) {
    int ti = wave + si * NWAVE;
    if (ti < TT) {
      bf16x8 ap[KSTEPS];
#pragma unroll
      for (int kk = 0; kk < KSTEPS; ++kk)
        ap[kk] = *reinterpret_cast<const bf16x8*>(&p_lds[(ti * 16 + l15) * PL + kk * 32 + l4 * 8]);
      int opix[4];
#pragma unroll
      for (int r = 0; r < 4; ++r) opix[r] = pixof(ti * 16 + l4 * 4 + r);
#pragma unroll
      for (int cj = 0; cj < 4; ++cj) {
        f32x4 o = {0.f, 0.f, 0.f, 0.f};
#pragma unroll
        for (int kk = 0; kk < KSTEPS; ++kk) {
          bf16x8 bv = *reinterpret_cast<const bf16x8*>(&vt_lds[(cj * 16 + l15) * PL + kk * 32 + l4 * 8]);
          o = __builtin_amdgcn_mfma_f32_16x16x32_bf16(ap[kk], bv, o, 0, 0, 0);
        }
#pragma unroll
        for (int r = 0; r < 4; ++r)
          Z[(size_t)opix[r] * 192 + SI * 64 + cj * 16 + l15] = f2bf(o[r]);
      }
    }
  }
}

// ---------------- conv_out: z [px][192] bf16 -> y1 [b,o,h,w] fp32 -----------
__launch_bounds__(256, 2)
__global__ void conv_out_kernel(const unsigned short* __restrict__ Z,
                                const unsigned short* __restrict__ Wo,
                                const float* __restrict__ bout,
                                float* __restrict__ Y1) {
  __shared__ unsigned short z_lds[64 * 40];
  __shared__ unsigned short w_lds[192 * 40];
  const int t = threadIdx.x, wave = t >> 6, lane = t & 63;
  const int l15 = lane & 15, l4 = lane >> 4;
  const int b = blockIdx.x / 225, px0 = (blockIdx.x % 225) * 64;
  const unsigned short* Zb = Z + ((size_t)b * HW + px0) * 192;
  const int wo0 = wave * 48;
  f32x4 acc[3][4];
#pragma unroll
  for (int m = 0; m < 3; ++m) {
    f32x4 bv;
#pragma unroll
    for (int r = 0; r < 4; ++r) bv[r] = bout[wo0 + m * 16 + l4 * 4 + r];
#pragma unroll
    for (int n = 0; n < 4; ++n) acc[m][n] = bv;
  }
  for (int kc = 0; kc < 6; ++kc) {
    const int c0 = kc * 32;
    {
      int px = t >> 2, c8 = (t & 3) * 8;
      *reinterpret_cast<u32x4*>(&z_lds[px * 40 + c8]) =
          *reinterpret_cast<const u32x4*>(Zb + (size_t)px * 192 + c0 + c8);
    }
#pragma unroll
    for (int p = 0; p < 3; ++p) {
      int o = p * 64 + (t >> 2), c8 = (t & 3) * 8;
      *reinterpret_cast<u32x4*>(&w_lds[o * 40 + c8]) =
          *reinterpret_cast<const u32x4*>(Wo + (size_t)o * 192 + c0 + c8);
    }
    __syncthreads();
    bf16x8 bfr[4];
#pragma unroll
    for (int n = 0; n < 4; ++n)
      bfr[n] = *reinterpret_cast<const bf16x8*>(&z_lds[(n * 16 + l15) * 40 + l4 * 8]);
#pragma unroll
    for (int m = 0; m < 3; ++m) {
      bf16x8 af = *reinterpret_cast<const bf16x8*>(&w_lds[(wo0 + m * 16 + l15) * 40 + l4 * 8]);
#pragma unroll
      for (int n = 0; n < 4; ++n)
        acc[m][n] = __builtin_amdgcn_mfma_f32_16x16x32_bf16(af, bfr[n], acc[m][n], 0, 0, 0);
    }
    __syncthreads();
  }
  float* Yb = Y1 + (size_t)b * 192 * HW + px0;
#pragma unroll
  for (int m = 0; m < 3; ++m) {
#pragma unroll
    for (int r = 0; r < 4; ++r) {
      int o = wo0 + m * 16 + l4 * 4 + r;
      float* dst = Yb + (size_t)o * HW + l15;
#pragma unroll
      for (int n = 0; n < 4; ++n) dst[n * 16] = acc[m][n][r];
    }
  }
}

// ---------------- launch ----------------------------------------------------
extern "C" void kernel_launch(void* const* d_in, const int* in_sizes, int n_in,
                              void* d_out, int out_size, void* d_ws, size_t ws_size,
                              hipStream_t stream) {
  const float* x = (const float*)d_in[0];
  const float* y = (const float*)d_in[1];
  const float* w_in = (const float*)d_in[2];
  const float* b_in = (const float*)d_in[3];
  const float* g = (const float*)d_in[4];
  const float* be = (const float*)d_in[5];
  const float* mu = (const float*)d_in[6];
  const float* va = (const float*)d_in[7];
  const float* w_out = (const float*)d_in[8];
  const float* b_out = (const float*)d_in[9];
  char* ws = (char*)d_ws;
  unsigned short* wx = (unsigned short*)(ws + 0);
  unsigned short* wy = (unsigned short*)(ws + 147456);
  unsigned short* wo = (unsigned short*)(ws + 221184);
  float* bx = (float*)(ws + 294912);
  float* by = (float*)(ws + 296448);
  unsigned short* xp = (unsigned short*)(ws + 297216);
  unsigned short* yq = (unsigned short*)(ws + 297216 + (size_t)115200 * 384 * 2);
  unsigned short* z  = (unsigned short*)(ws + 297216 + (size_t)115200 * 384 * 2 +
                                         (size_t)115200 * 192 * 2);
  float* out = (float*)d_out;

  prep_kernel<<<576, 256, 0, stream>>>(w_in, b_in, g, be, mu, va, w_out, wx, wy, wo, bx, by);
  conv_in_kernel<384><<<1800, 256, 0, stream>>>(x, wx, bx, xp);
  conv_in_kernel<192><<<1800, 256, 0, stream>>>(y, wy, by, yq);
  attn_kernel<4, 0, 64><<<7200, 64, 0, stream>>>(xp, yq, z, out + 22118400);
  attn_kernel<8, 1, 256><<<1800, 256, 0, stream>>>(xp, yq, z, out + 23961600);
  attn_kernel<12, 2, 256><<<800, 256, 0, stream>>>(xp, yq, z, out + 31334400);
  conv_out_kernel<<<1800, 256, 0, stream>>>(z, wo, b_out, out);
}